// Round 18
// baseline (118.597 us; speedup 1.0000x reference)
//
#include <hip/hip_runtime.h>

typedef float f32x4 __attribute__((ext_vector_type(4)));
typedef _Float16 h8 __attribute__((ext_vector_type(8)));
typedef unsigned short us8 __attribute__((ext_vector_type(8)));

#define DEV __device__ __forceinline__

constexpr int Bb = 32, Nn = 1024, Mm = 576, Dd = 768;
constexpr float L2E = 1.44269504088896340736f;

// ws layout (ushort elems), fragment-major for 16x16x32 f16 MFMA:
//   Kf: [b][kvtile 36][dc 24][lane 64][8]   B-frag: K[kvt*16+(l&15)][dc*32+(l>>4)*8+j]
//   Vf: [b][kc 18][dtile 48][lane 64][8]    B-frag: V[kc*32+(l>>4)*8+j][dt*16+(l&15)]
constexpr size_t KF_ELEMS = (size_t)Bb * 36 * 24 * 512;  // 14,155,776

DEV unsigned short f2h(float x) {
  _Float16 h = (_Float16)x;
  return __builtin_bit_cast(unsigned short, h);
}
DEV void gll16(const void* g, void* l) {
  __builtin_amdgcn_global_load_lds(
      (const __attribute__((address_space(1))) void*)g,
      (__attribute__((address_space(3))) void*)l, 16, 0, 0);
}

// ---------------- pre-pass (R17-proven): K read ONCE, LDS-staged, both outputs coalesced.
__global__ __launch_bounds__(256)
void fusion_prep(const float* __restrict__ K, unsigned short* __restrict__ Kf,
                 unsigned short* __restrict__ Vf)
{
  __shared__ float ks[64][33];
  const int t   = threadIdx.x;
  const int blk = blockIdx.x;
  const int b    = blk / 18;
  const int r2   = blk % 18;
  const int rt   = r2 >> 1;        // kv rows [rt*64, +64)
  const int half = r2 & 1;         // dc in [half*12, +12)
  const int l    = t & 63;

  const int row0 = t >> 3, c40 = t & 7;
  const int row1 = (t + 256) >> 3;
  const float* Kb = K + ((size_t)(b * Mm + rt * 64)) * Dd;

  const int kvt_l = t >> 6;
  const int kf_r  = kvt_l * 16 + (l & 15);
  const int kf_c  = (l >> 4) * 8;
  const int kc_l = t >> 7;
  const int dtl  = (t >> 6) & 1;
  const int vf_r = kc_l * 32 + (l >> 4) * 8;
  const int vf_c = dtl * 16 + (l & 15);

#pragma unroll 1
  for (int dc = half * 12; dc < half * 12 + 12; ++dc) {
    __syncthreads();
    f32x4 v0 = *(const f32x4*)(Kb + (size_t)row0 * Dd + dc * 32 + c40 * 4);
    f32x4 v1 = *(const f32x4*)(Kb + (size_t)row1 * Dd + dc * 32 + c40 * 4);
    *(f32x4*)&ks[row0][c40 * 4] = v0;
    *(f32x4*)&ks[row1][c40 * 4] = v1;
    __syncthreads();
    {
      us8 h;
#pragma unroll
      for (int j = 0; j < 8; ++j) h[j] = f2h(ks[kf_r][kf_c + j]);
      *(us8*)&Kf[(((size_t)((b * 36 + rt * 4 + kvt_l) * 24 + dc)) << 9) + l * 8] = h;
    }
    {
      us8 o;
#pragma unroll
      for (int j = 0; j < 8; ++j) o[j] = f2h(ks[vf_r + j][vf_c]);
      *(us8*)&Vf[(((size_t)((b * 18 + rt * 2 + kc_l) * 48 + dc * 2 + dtl)) << 9) + l * 8] = o;
    }
  }
}

// ---------------- main: 512 thr / 8 FAT waves, 1 block/CU -> 2 waves/SIMD -> 256 regs.
// Per wave QK: 64q x 144kv (acc[4][9]=144 AGPR); K frags amortized over 2x q rows.
// LDS (bytes): bufK[2] @ {0,36864}; qbuf[2] @ 73728+{0,8192} ([qtile8][lane64][16B]).
//              sP (128x576 f16, pitch 1152, XOR swizzle) aliases 0..147456 after QK.
__global__ __launch_bounds__(512, 1)
void fusion_main(const float* __restrict__ Q, const unsigned short* __restrict__ Kf,
                 const unsigned short* __restrict__ Vf, float* __restrict__ Out)
{
  __shared__ alignas(16) unsigned char lds[147456];
  __shared__ float sRa[4][128];
  __shared__ float sRb[4][128];

  const int tid  = threadIdx.x;
  const int lane = tid & 63;
  const int w    = tid >> 6;      // 0..7
  const int g    = lane >> 4;
  const int ln   = lane & 15;
  const int wqk  = w >> 2;        // QK: 0..1, q rows [wqk*64,+64)
  const int wkv  = w & 3;         // QK: kv slice [wkv*144,+144)
  const int wq2  = w >> 2;        // PV: 0..1, q rows [wq2*64,+64)
  const int wd4  = w & 3;         // PV: d slice [wd4*192,+192)

  // XCD swizzle
  const int bid = blockIdx.x;
  const int xcd = bid & 7, ii = bid >> 3;
  const int b  = (xcd << 2) | (ii >> 3);
  const int q0 = (ii & 7) * 128;

  const float* Qb = Q + ((size_t)(b * Nn + q0)) * Dd;
  const unsigned char* KfB = (const unsigned char*)Kf + ((size_t)(b * 36 * 24) << 10);
  const unsigned short* VfB = Vf + ((size_t)(b * 18 * 48) << 9);

  // K staging: 36 units over 8 waves (4x5 + 4x4)
  const int nu = (w < 4) ? 5 : 4;
  const int u0 = (w < 4) ? w * 5 : 20 + (w - 4) * 4;

  // Q staging: thread -> one 16B frag slot: qtile tid>>6, lane slot
  const int qt_s = tid >> 6;
  const float* qsrc = Qb + (size_t)(qt_s * 16 + (lane & 15)) * Dd + (lane >> 4) * 8;
  unsigned char* qdst = lds + 73728 + qt_s * 1024 + lane * 16;

  // ---------------- prologue: Q(0) regs -> K(0) gll16 -> cvt/store -> sync
  f32x4 acc_init = (f32x4){0.f, 0.f, 0.f, 0.f};
  {
    f32x4 a0 = *(const f32x4*)qsrc;
    f32x4 a1 = *(const f32x4*)(qsrc + 4);
#pragma unroll
    for (int j = 0; j < 5; ++j)
      if (j < nu)
        gll16(KfB + ((size_t)((u0 + j) * 24) << 10) + (lane << 4), lds + (u0 + j) * 1024);
    us8 h0;
#pragma unroll
    for (int k = 0; k < 4; ++k) {
      h0[k]   = f2h(a0[k] * L2E);
      h0[k+4] = f2h(a1[k] * L2E);
    }
    *(us8*)qdst = h0;
    __syncthreads();
  }

  // ---------------- QK: acc[mt 4][nt 9] = [64 q][144 kv]; 2-buffer pipeline
  f32x4 acc[4][9];
#pragma unroll
  for (int mt = 0; mt < 4; ++mt)
#pragma unroll
    for (int nt = 0; nt < 9; ++nt) acc[mt][nt] = acc_init;

#pragma unroll 1
  for (int c = 0; c < 24; ++c) {
    const int cur = c & 1, nxt = cur ^ 1;
    const bool stg = (c < 23);
    f32x4 a0, a1;
    if (stg) {
      // Q loads FIRST (oldest vmem) so cvt's auto-wait keeps gll16s in flight
      const float* qs = qsrc + (size_t)(c + 1) * 32;
      a0 = *(const f32x4*)qs;
      a1 = *(const f32x4*)(qs + 4);
#pragma unroll
      for (int j = 0; j < 5; ++j)
        if (j < nu)
          gll16(KfB + ((size_t)((u0 + j) * 24 + c + 1) << 10) + (lane << 4),
                lds + nxt * 36864 + (u0 + j) * 1024);
    }
    // compute on cur
    const unsigned char* qb = lds + 73728 + cur * 8192;
    const unsigned char* kb = lds + cur * 36864;
    h8 qh[4];
#pragma unroll
    for (int mt = 0; mt < 4; ++mt)
      qh[mt] = *(const h8*)(qb + (wqk * 4 + mt) * 1024 + lane * 16);
    __builtin_amdgcn_s_setprio(1);
#pragma unroll
    for (int nt = 0; nt < 9; ++nt) {
      const h8 kf = *(const h8*)(kb + (wkv * 9 + nt) * 1024 + lane * 16);
#pragma unroll
      for (int mt = 0; mt < 4; ++mt)
        acc[mt][nt] = __builtin_amdgcn_mfma_f32_16x16x32_f16(qh[mt], kf, acc[mt][nt], 0, 0, 0);
    }
    __builtin_amdgcn_s_setprio(0);
    if (stg) {
      us8 h0;
#pragma unroll
      for (int k = 0; k < 4; ++k) {
        h0[k]   = f2h(a0[k] * L2E);
        h0[k+4] = f2h(a1[k] * L2E);
      }
      *(us8*)(qdst + nxt * 8192) = h0;
    }
    __syncthreads();
  }

  // ---------------- one-shot softmax (exp2 domain; Q pre-scaled by log2 e)
  float pm[4][4];
#pragma unroll
  for (int mt = 0; mt < 4; ++mt)
#pragma unroll
    for (int i2 = 0; i2 < 4; ++i2) {
      float v = acc[mt][0][i2];
#pragma unroll
      for (int nt = 1; nt < 9; ++nt) v = fmaxf(v, acc[mt][nt][i2]);
      pm[mt][i2] = v;
    }
#pragma unroll
  for (int mk = 1; mk < 16; mk <<= 1)
#pragma unroll
    for (int mt = 0; mt < 4; ++mt)
#pragma unroll
      for (int i2 = 0; i2 < 4; ++i2)
        pm[mt][i2] = fmaxf(pm[mt][i2], __shfl_xor(pm[mt][i2], mk, 64));
  if (ln == 0) {
#pragma unroll
    for (int mt = 0; mt < 4; ++mt)
#pragma unroll
      for (int i2 = 0; i2 < 4; ++i2)
        sRa[wkv][wqk * 64 + mt * 16 + g * 4 + i2] = pm[mt][i2];
  }
  __syncthreads();

  float mfin[4][4], ps[4][4];
#pragma unroll
  for (int mt = 0; mt < 4; ++mt)
#pragma unroll
    for (int i2 = 0; i2 < 4; ++i2) {
      const int rw = wqk * 64 + mt * 16 + g * 4 + i2;
      mfin[mt][i2] = fmaxf(fmaxf(sRa[0][rw], sRa[1][rw]), fmaxf(sRa[2][rw], sRa[3][rw]));
      ps[mt][i2] = 0.f;
    }
#pragma unroll
  for (int mt = 0; mt < 4; ++mt)
#pragma unroll
    for (int nt = 0; nt < 9; ++nt)
#pragma unroll
      for (int i2 = 0; i2 < 4; ++i2) {
        const float p = exp2f(acc[mt][nt][i2] - mfin[mt][i2]);
        acc[mt][nt][i2] = p;
        ps[mt][i2] += p;
      }
#pragma unroll
  for (int mk = 1; mk < 16; mk <<= 1)
#pragma unroll
    for (int mt = 0; mt < 4; ++mt)
#pragma unroll
      for (int i2 = 0; i2 < 4; ++i2)
        ps[mt][i2] += __shfl_xor(ps[mt][i2], mk, 64);
  if (ln == 0) {
#pragma unroll
    for (int mt = 0; mt < 4; ++mt)
#pragma unroll
      for (int i2 = 0; i2 < 4; ++i2)
        sRb[wkv][wqk * 64 + mt * 16 + g * 4 + i2] = ps[mt][i2];
  }
  __syncthreads();

  // normalize P -> swizzled sP (aliases dead bufK/qbuf)
  {
    unsigned short* sPp = (unsigned short*)lds;
#pragma unroll
    for (int mt = 0; mt < 4; ++mt)
#pragma unroll
      for (int i2 = 0; i2 < 4; ++i2) {
        const int rw = wqk * 64 + mt * 16 + g * 4 + i2;
        const float inv = 1.0f / ((sRb[0][rw] + sRb[1][rw]) + (sRb[2][rw] + sRb[3][rw]));
#pragma unroll
        for (int nt = 0; nt < 9; ++nt) {
          const int u = wkv * 18 + nt * 2 + (ln >> 3);
          sPp[rw * 576 + ((u ^ (rw & 7)) << 3) + (ln & 7)] = f2h(acc[mt][nt][i2] * inv);
        }
      }
  }
  __syncthreads();

  // ---------------- PV: [64q x 192d]/wave, 2 passes of 96d; vf dbuf (2x unroll)
#pragma unroll 1
  for (int p = 0; p < 2; ++p) {
    f32x4 O[4][6];
#pragma unroll
    for (int mt = 0; mt < 4; ++mt)
#pragma unroll
      for (int nt = 0; nt < 6; ++nt) O[mt][nt] = (f32x4){0.f, 0.f, 0.f, 0.f};

    // dtile base: dt = wd4*12 + p*6 + nt
    const unsigned short* vbase = VfB + ((size_t)(wd4 * 12 + p * 6) << 9) + lane * 8;
    h8 vfA[6], vfB2[6];
#pragma unroll
    for (int nt = 0; nt < 6; ++nt)
      vfA[nt] = *(const h8*)(vbase + ((size_t)nt << 9));

#pragma unroll 1
    for (int kc = 0; kc < 18; kc += 2) {
#pragma unroll
      for (int nt = 0; nt < 6; ++nt)
        vfB2[nt] = *(const h8*)(vbase + ((size_t)((kc + 1) * 48 + nt) << 9));
      {
        h8 pa[4];
#pragma unroll
        for (int mt = 0; mt < 4; ++mt) {
          const int row = wq2 * 64 + mt * 16 + ln;
          const int u = kc * 4 + g;
          pa[mt] = *(const h8*)(lds + row * 1152 + ((u ^ (row & 7)) << 4));
        }
#pragma unroll
        for (int nt = 0; nt < 6; ++nt)
#pragma unroll
          for (int mt = 0; mt < 4; ++mt)
            O[mt][nt] = __builtin_amdgcn_mfma_f32_16x16x32_f16(pa[mt], vfA[nt], O[mt][nt], 0, 0, 0);
      }
      if (kc < 16) {
#pragma unroll
        for (int nt = 0; nt < 6; ++nt)
          vfA[nt] = *(const h8*)(vbase + ((size_t)((kc + 2) * 48 + nt) << 9));
      }
      {
        h8 pa[4];
#pragma unroll
        for (int mt = 0; mt < 4; ++mt) {
          const int row = wq2 * 64 + mt * 16 + ln;
          const int u = (kc + 1) * 4 + g;
          pa[mt] = *(const h8*)(lds + row * 1152 + ((u ^ (row & 7)) << 4));
        }
#pragma unroll
        for (int nt = 0; nt < 6; ++nt)
#pragma unroll
          for (int mt = 0; mt < 4; ++mt)
            O[mt][nt] = __builtin_amdgcn_mfma_f32_16x16x32_f16(pa[mt], vfB2[nt], O[mt][nt], 0, 0, 0);
      }
    }

    float* ob = Out + ((size_t)(b * Nn + q0 + wq2 * 64)) * Dd;
#pragma unroll
    for (int mt = 0; mt < 4; ++mt)
#pragma unroll
      for (int nt = 0; nt < 6; ++nt)
#pragma unroll
        for (int i2 = 0; i2 < 4; ++i2)
          ob[(size_t)(mt * 16 + g * 4 + i2) * Dd + wd4 * 192 + p * 96 + nt * 16 + ln] = O[mt][nt][i2];
  }
}

extern "C" void kernel_launch(void* const* d_in, const int* in_sizes, int n_in,
                              void* d_out, int out_size, void* d_ws, size_t ws_size,
                              hipStream_t stream) {
  const float* Q = (const float*)d_in[0];
  const float* K = (const float*)d_in[1];
  float* Out = (float*)d_out;
  unsigned short* Kf = (unsigned short*)d_ws;
  unsigned short* Vf = Kf + KF_ELEMS;
  fusion_prep<<<dim3(Bb * 18), dim3(256), 0, stream>>>(K, Kf, Vf);
  fusion_main<<<dim3(Bb * 8), dim3(512), 0, stream>>>(Q, Kf, Vf, Out);
}